// Round 11
// baseline (1906.136 us; speedup 1.0000x reference)
//
#include <hip/hip_runtime.h>
#include <cstdint>
#include <cstddef>

// Problem constants
#define Bq  4
#define Tq  2048
#define Cq  1024
#define Hq  16
#define Dq  64
#define BTq 8192
#define C3q 3072

// ---- DIAGNOSTIC ROUND 2: attn (R6 structure) rep=3, gemm<0> (LDS-transpose
// epilogue) rep=10. True per-kernel time = dur_us / rep. Compare gemm<0> to
// R9's scatter-epilogue baseline of 140us/rep, FETCH 86MB/rep. ----

using bf16x8 = __attribute__((ext_vector_type(8))) short;
using f32x4  = __attribute__((ext_vector_type(4))) float;
using us4    = __attribute__((ext_vector_type(4))) unsigned short;

__device__ __forceinline__ unsigned short f2bf(float f) {
  unsigned u = __builtin_bit_cast(unsigned, f);
  return (unsigned short)((u + 0x7fffu + ((u >> 16) & 1u)) >> 16);  // RNE
}
__device__ __forceinline__ float bf2f(unsigned short h) {
  return __builtin_bit_cast(float, (unsigned)h << 16);
}

__device__ __forceinline__ void gload_lds16(const void* g, void* l) {
  __builtin_amdgcn_global_load_lds(
      (const __attribute__((address_space(1))) void*)g,
      (__attribute__((address_space(3))) void*)l, 16, 0, 0);
}

// ---------------- fp32 -> bf16 conversion ----------------
__global__ __launch_bounds__(256) void cvt_kernel(const float* __restrict__ src,
                                                  unsigned short* __restrict__ dst, int n4) {
  int i = blockIdx.x * 256 + threadIdx.x;
  int stride = gridDim.x * 256;
  for (; i < n4; i += stride) {
    float4 v = reinterpret_cast<const float4*>(src)[i];
    us4 o = { f2bf(v.x), f2bf(v.y), f2bf(v.z), f2bf(v.w) };
    reinterpret_cast<us4*>(dst)[i] = o;
  }
}

// ---------------- 128x128-tile bf16 MFMA GEMM ----------------
// EPI 0: LDS-transpose epilogue -> coalesced Q/K [bh,t,d], Vt [bh,d,t] (bf16)
// EPI 1: direct fp32 Cout[M,N]
template<int EPI>
__global__ __launch_bounds__(256) void gemm128(
    const unsigned short* __restrict__ A, const unsigned short* __restrict__ Bw,
    const float* __restrict__ bias,
    unsigned short* __restrict__ Qb, unsigned short* __restrict__ Kb,
    unsigned short* __restrict__ Vtb, float* __restrict__ Cout,
    int M, int N, int K, int rep)
{
  __shared__ __align__(16) unsigned short S[8704];   // As | Bs, reused as Ls[64][136]
  unsigned short* As = S;
  unsigned short* Bs = S + 4096;
  const int n0 = blockIdx.x * 128, m0 = blockIdx.y * 128;
  const int tid = threadIdx.x;
  const int w = tid >> 6, l = tid & 63, r = l & 15, g = l >> 4;
  const int wm = w >> 1, wn = w & 1;
  const int ldRow = tid >> 2, ldCol = (tid & 3) * 8;

  const unsigned short* Ar0 = A  + (size_t)(m0 +      ldRow) * K + ldCol;
  const unsigned short* Ar1 = A  + (size_t)(m0 + 64 + ldRow) * K + ldCol;
  const unsigned short* Br0 = Bw + (size_t)(n0 +      ldRow) * K + ldCol;
  const unsigned short* Br1 = Bw + (size_t)(n0 + 64 + ldRow) * K + ldCol;
  char* Ab0 = (char*)As        + w * 1024;
  char* Ab1 = (char*)As + 4096 + w * 1024;
  char* Bb0 = (char*)Bs        + w * 1024;
  char* Bb1 = (char*)Bs + 4096 + w * 1024;

  for (int it = 0; it < rep; ++it) {
    f32x4 acc[4][4] = {};
    for (int k0 = 0; k0 < K; k0 += 32) {
      __syncthreads();
      gload_lds16(Ar0 + k0, Ab0);
      gload_lds16(Ar1 + k0, Ab1);
      gload_lds16(Br0 + k0, Bb0);
      gload_lds16(Br1 + k0, Bb1);
      __syncthreads();
      bf16x8 a[4], b[4];
      #pragma unroll
      for (int i = 0; i < 4; ++i) a[i] = *(const bf16x8*)&As[(wm*64 + i*16 + r)*32 + g*8];
      #pragma unroll
      for (int j = 0; j < 4; ++j) b[j] = *(const bf16x8*)&Bs[(wn*64 + j*16 + r)*32 + g*8];
      #pragma unroll
      for (int i = 0; i < 4; ++i)
        #pragma unroll
        for (int j = 0; j < 4; ++j)
          acc[i][j] = __builtin_amdgcn_mfma_f32_16x16x32_bf16(a[i], b[j], acc[i][j], 0, 0, 0);
    }

    if (EPI == 0) {
      // LDS-transpose epilogue: stage acc into Ls[64 cols][136], store coalesced
      const int which = n0 >> 10;
      __syncthreads();
      #pragma unroll
      for (int hh = 0; hh < 2; ++hh) {
        if (hh) __syncthreads();
        if (wn == hh) {
          #pragma unroll
          for (int i = 0; i < 4; ++i)
            #pragma unroll
            for (int j = 0; j < 4; ++j) {
              int c = j*16 + r;
              float bv = bias[n0 + hh*64 + c];
              int t = wm*64 + i*16 + 4*g;
              us4 pk = { f2bf(acc[i][j][0]+bv), f2bf(acc[i][j][1]+bv),
                         f2bf(acc[i][j][2]+bv), f2bf(acc[i][j][3]+bv) };
              *(us4*)&S[c*136 + t] = pk;
            }
        }
        __syncthreads();
        const int hd = (n0 & 1023) + hh*64;
        const int h  = hd >> 6;
        if (which == 2) {
          int d = tid >> 2, tp = tid & 3;
          int bh = (m0 >> 11)*Hq + h;
          size_t base = ((size_t)(bh*Dq + d))*Tq + (m0 & 2047) + tp*32;
          const unsigned short* Lr = &S[d*136 + tp*32];
          #pragma unroll
          for (int q4 = 0; q4 < 4; ++q4)
            *(bf16x8*)&Vtb[base + q4*8] = *(const bf16x8*)&Lr[q4*8];
        } else {
          unsigned short* dst = which ? Kb : Qb;
          int t = tid >> 1, dp = tid & 1;
          int gr = m0 + t;
          int bh = (gr >> 11)*Hq + h;
          size_t base = ((size_t)(bh*Tq + (gr & 2047)))*Dq + dp*32;
          #pragma unroll
          for (int q4 = 0; q4 < 4; ++q4) {
            bf16x8 vv;
            #pragma unroll
            for (int e = 0; e < 8; ++e)
              vv[e] = (short)S[(dp*32 + q4*8 + e)*136 + t];
            *(bf16x8*)&dst[base + q4*8] = vv;
          }
        }
      }
    } else {
      #pragma unroll
      for (int i = 0; i < 4; ++i)
        #pragma unroll
        for (int j = 0; j < 4; ++j) {
          int gc = n0 + wn*64 + j*16 + r;
          float bv = bias[gc];
          #pragma unroll
          for (int jj = 0; jj < 4; ++jj) {
            int gr = m0 + wm*64 + i*16 + 4*g + jj;
            Cout[(size_t)gr * N + gc] = acc[i][j][jj] + bv;
          }
        }
    }
  }
}

// ---------------- causal attention (R6 structure, wave-specialized pass B) -----------
#define PROWB 4224   // row stride bytes (2112 bf16) = 33*128
#define XMASK(row_) ((((row_) & 7) << 4) ^ ((((row_) >> 2) & 3) << 5))

__global__ __launch_bounds__(512, 4) void attn_kernel(
    const unsigned short* __restrict__ Qb, const unsigned short* __restrict__ Kb,
    const unsigned short* __restrict__ Vtb,
    float* __restrict__ attn, unsigned short* __restrict__ ctxb, int rep)
{
  __shared__ __align__(16) unsigned short P[16][2112];   // 66 KB
  __shared__ float red[8][32];
  __shared__ float invl_s[32];

  const int p  = blockIdx.x;
  const int bh = blockIdx.y;
  const int tid = threadIdx.x, w = tid >> 6, l = tid & 63, r = l & 15, g = l >> 4;
  const int qbA = p * 16, qbB = (127 - p) * 16;
  const int NA = (qbA + 16 + 31) >> 5;
  const int NB = (qbB + 16 + 31) >> 5;   // NA + NB == 65
  const int LAc = NA * 32, LBc = NB * 32;

  const unsigned short* Qp = Qb  + (size_t)bh * Tq * Dq;
  const unsigned short* Kp = Kb  + (size_t)bh * Tq * Dq;
  const unsigned short* Vp = Vtb + (size_t)bh * Dq * Tq;
  char* Pmut = (char*)&P[0][0];

  bf16x8 aqA0 = *(const bf16x8*)&Qp[(size_t)(qbA + r)*Dq      + g*8];
  bf16x8 aqA1 = *(const bf16x8*)&Qp[(size_t)(qbA + r)*Dq + 32 + g*8];
  bf16x8 aqB0 = *(const bf16x8*)&Qp[(size_t)(qbB + r)*Dq      + g*8];
  bf16x8 aqB1 = *(const bf16x8*)&Qp[(size_t)(qbB + r)*Dq + 32 + g*8];

#define LOADK(ci_, D00, D01, D10, D11)                                              \
  {                                                                                 \
    int cj_ = ((ci_) < NA) ? (ci_) : (ci_) - NA;                                    \
    int k0c_ = cj_ * 32;                                                            \
    D00 = *(const bf16x8*)&Kp[(size_t)(k0c_ + r)*Dq      + g*8];                    \
    D01 = *(const bf16x8*)&Kp[(size_t)(k0c_ + r)*Dq + 32 + g*8];                    \
    D10 = *(const bf16x8*)&Kp[(size_t)(k0c_ + 16 + r)*Dq      + g*8];               \
    D11 = *(const bf16x8*)&Kp[(size_t)(k0c_ + 16 + r)*Dq + 32 + g*8];               \
  }

  for (int it = 0; it < rep; ++it) {
    __syncthreads();
    float lsumA[4] = {0.f,0.f,0.f,0.f}, lsumB[4] = {0.f,0.f,0.f,0.f};

    // ---- pass A ----
    {
      bf16x8 k00, k01, k10, k11, n00, n01, n10, n11;
      int ci = w;
      if (ci < 65) LOADK(ci, k00, k01, k10, k11);
      for (; ci < 65; ci += 8) {
        if (ci + 8 < 65) LOADK(ci + 8, n00, n01, n10, n11);
        const bool isA = ci < NA;
        const int cj  = isA ? ci : ci - NA;
        const int k0c = cj * 32;
        const int qb_ = isA ? qbA : qbB;
        const int cb_ = isA ? k0c : LAc + k0c;
        bf16x8 q0_ = isA ? aqA0 : aqB0;
        bf16x8 q1_ = isA ? aqA1 : aqB1;
        f32x4 z = {0.f,0.f,0.f,0.f};
        __builtin_amdgcn_s_setprio(1);
        f32x4 s0 = __builtin_amdgcn_mfma_f32_16x16x32_bf16(q0_, k00, z, 0, 0, 0);
        s0 = __builtin_amdgcn_mfma_f32_16x16x32_bf16(q1_, k01, s0, 0, 0, 0);
        f32x4 s1 = __builtin_amdgcn_mfma_f32_16x16x32_bf16(q0_, k10, z, 0, 0, 0);
        s1 = __builtin_amdgcn_mfma_f32_16x16x32_bf16(q1_, k11, s1, 0, 0, 0);
        __builtin_amdgcn_s_setprio(0);
        float tch[4];
        #pragma unroll
        for (int jj = 0; jj < 4; ++jj) {
          int q = qb_ + 4*g + jj;
          float p0 = (k0c + r      <= q) ? __expf(s0[jj]*0.125f) : 0.f;
          float p1 = (k0c + 16 + r <= q) ? __expf(s1[jj]*0.125f) : 0.f;
          tch[jj] = p0 + p1;
          int row = 4*g + jj, xm = XMASK(row);
          *(unsigned short*)(Pmut + row*PROWB + (((cb_ + r)*2)      ^ xm)) = f2bf(p0);
          *(unsigned short*)(Pmut + row*PROWB + (((cb_ + 16 + r)*2) ^ xm)) = f2bf(p1);
        }
        if (isA) { lsumA[0]+=tch[0]; lsumA[1]+=tch[1]; lsumA[2]+=tch[2]; lsumA[3]+=tch[3]; }
        else     { lsumB[0]+=tch[0]; lsumB[1]+=tch[1]; lsumB[2]+=tch[2]; lsumB[3]+=tch[3]; }
        k00 = n00; k01 = n01; k10 = n10; k11 = n11;
      }
    }

    // ---- row-sum reduction ----
    #pragma unroll
    for (int jj = 0; jj < 4; ++jj) {
      float sa = lsumA[jj], sb = lsumB[jj];
      #pragma unroll
      for (int off = 1; off < 16; off <<= 1) {
        sa += __shfl_xor(sa, off, 64);
        sb += __shfl_xor(sb, off, 64);
      }
      if (r == 0) { red[w][4*g + jj] = sa; red[w][16 + 4*g + jj] = sb; }
    }
    __syncthreads();
    if (tid < 32) {
      float s = 0.f;
      #pragma unroll
      for (int ww = 0; ww < 8; ++ww) s += red[ww][tid];
      invl_s[tid] = 1.f / s;
    }
    __syncthreads();

    // ---- pass B: wave-specialized, concurrent ----
    if (w < 4) {
      #pragma unroll
      for (int s = 0; s < 2; ++s) {
        const int idx   = s * 256 + tid;
        const int s16   = idx >> 8;
        const int row16 = (idx >> 4) & 15;
        const int seg   = (idx & 15) * 8;
        const int xm16  = XMASK(row16);
        const char* Prow = Pmut + row16 * PROWB;
        const int Lc    = s16 ? LBc : LAc;
        const int cbase = s16 ? LAc : 0;
        float inv = invl_s[s16*16 + row16];
        size_t ob = ((size_t)bh*Tq + (s16 ? qbB : qbA) + row16) * Tq;
        for (int cb = seg; cb < Tq; cb += 128) {
          f32x4 v0 = {0.f,0.f,0.f,0.f}, v1 = {0.f,0.f,0.f,0.f};
          if (cb < Lc) {
            bf16x8 pv = *(const bf16x8*)(Prow + (((cbase + cb)*2) ^ xm16));
            v0[0]=bf2f((unsigned short)pv[0])*inv; v0[1]=bf2f((unsigned short)pv[1])*inv;
            v0[2]=bf2f((unsigned short)pv[2])*inv; v0[3]=bf2f((unsigned short)pv[3])*inv;
            v1[0]=bf2f((unsigned short)pv[4])*inv; v1[1]=bf2f((unsigned short)pv[5])*inv;
            v1[2]=bf2f((unsigned short)pv[6])*inv; v1[3]=bf2f((unsigned short)pv[7])*inv;
          }
          __builtin_nontemporal_store(v0, (f32x4*)&attn[ob + cb]);
          __builtin_nontemporal_store(v1, (f32x4*)&attn[ob + cb + 4]);
        }
      }
    } else {
      const int dblk = w - 4;
      const char* Pr = Pmut + r * PROWB;
      const int xr = XMASK(r);
      const unsigned short* Vrow = &Vp[(size_t)(dblk*16 + r) * Tq];
      f32x4 coA0 = {0.f,0.f,0.f,0.f}, coA1 = {0.f,0.f,0.f,0.f};
      f32x4 coB0 = {0.f,0.f,0.f,0.f}, coB1 = {0.f,0.f,0.f,0.f};
      bf16x8 pa, bv, pan, bvn;
      {
        pa = *(const bf16x8*)(Pr + (((0 + g*8)*2) ^ xr));
        bv = *(const bf16x8*)&Vrow[g*8];
      }
      for (int ci = 0; ci < 65; ++ci) {
        if (ci + 1 < 65) {
          int cn = ci + 1;
          int cj = (cn < NA) ? cn : cn - NA;
          int cb = (cn < NA) ? cn*32 : LAc + cj*32;
          pan = *(const bf16x8*)(Pr + (((cb + g*8)*2) ^ xr));
          bvn = *(const bf16x8*)&Vrow[cj*32 + g*8];
        }
        if (ci < NA) {
          if (ci & 1) coA1 = __builtin_amdgcn_mfma_f32_16x16x32_bf16(pa, bv, coA1, 0, 0, 0);
          else        coA0 = __builtin_amdgcn_mfma_f32_16x16x32_bf16(pa, bv, coA0, 0, 0, 0);
        } else {
          if (ci & 1) coB1 = __builtin_amdgcn_mfma_f32_16x16x32_bf16(pa, bv, coB1, 0, 0, 0);
          else        coB0 = __builtin_amdgcn_mfma_f32_16x16x32_bf16(pa, bv, coB0, 0, 0, 0);
        }
        pa = pan; bv = bvn;
      }
      const int b = bh >> 4, h = bh & 15;
      #pragma unroll
      for (int jj = 0; jj < 4; ++jj) {
        int tA = qbA + 4*g + jj;
        ctxb[(size_t)(b*Tq + tA)*Cq + h*Dq + dblk*16 + r] =
            f2bf((coA0[jj] + coA1[jj]) * invl_s[4*g + jj]);
        int tB = qbB + 4*g + jj;
        ctxb[(size_t)(b*Tq + tB)*Cq + h*Dq + dblk*16 + r] =
            f2bf((coB0[jj] + coB1[jj]) * invl_s[16 + 4*g + jj]);
      }
    }
  }
#undef LOADK
}

// ---------------- launch ----------------
extern "C" void kernel_launch(void* const* d_in, const int* in_sizes, int n_in,
                              void* d_out, int out_size, void* d_ws, size_t ws_size,
                              hipStream_t stream) {
  const float* x     = (const float*)d_in[0];
  const float* qkv_w = (const float*)d_in[1];
  const float* qkv_b = (const float*)d_in[2];
  const float* out_w = (const float*)d_in[3];
  const float* out_b = (const float*)d_in[4];
  float* out  = (float*)d_out;
  float* attn = out + (size_t)BTq * Cq;

  char* ws = (char*)d_ws;
  unsigned short* xb    = (unsigned short*)(ws);
  unsigned short* wqkvb = (unsigned short*)(ws + (16u << 20));
  unsigned short* woutb = (unsigned short*)(ws + (22u << 20));
  unsigned short* Qb    = (unsigned short*)(ws + (24u << 20));
  unsigned short* Kb    = (unsigned short*)(ws + (40u << 20));
  unsigned short* Vtb   = (unsigned short*)(ws + (56u << 20));
  unsigned short* ctxb  = (unsigned short*)(ws + (72u << 20));

  // DIAGNOSTIC repeats: true time = dur_us / rep
  const int G0_REP = 10, ATTN_REP = 3;

  cvt_kernel<<<2048, 256, 0, stream>>>(x,     xb,    (BTq * Cq) / 4);
  cvt_kernel<<<1024, 256, 0, stream>>>(qkv_w, wqkvb, (C3q * Cq) / 4);
  cvt_kernel<<<512,  256, 0, stream>>>(out_w, woutb, (Cq * Cq) / 4);

  dim3 g1(C3q / 128, BTq / 128);
  gemm128<0><<<g1, 256, 0, stream>>>(xb, wqkvb, qkv_b, Qb, Kb, Vtb, nullptr,
                                     BTq, C3q, Cq, G0_REP);

  dim3 g2(64, Bq * Hq);
  attn_kernel<<<g2, 512, 0, stream>>>(Qb, Kb, Vtb, attn, ctxb, ATTN_REP);

  dim3 g3(Cq / 128, BTq / 128);
  gemm128<1><<<g3, 256, 0, stream>>>(ctxb, woutb, out_b, nullptr, nullptr, nullptr,
                                     out, BTq, Cq, Cq, 1);
}

// Round 12
// 493.101 us; speedup vs baseline: 3.8656x; 3.8656x over previous
//
#include <hip/hip_runtime.h>
#include <cstdint>
#include <cstddef>

// Problem constants
#define Bq  4
#define Tq  2048
#define Cq  1024
#define Hq  16
#define Dq  64
#define BTq 8192
#define C3q 3072

using bf16x8 = __attribute__((ext_vector_type(8))) short;
using f32x4  = __attribute__((ext_vector_type(4))) float;
using us4    = __attribute__((ext_vector_type(4))) unsigned short;

__device__ __forceinline__ unsigned short f2bf(float f) {
  unsigned u = __builtin_bit_cast(unsigned, f);
  return (unsigned short)((u + 0x7fffu + ((u >> 16) & 1u)) >> 16);  // RNE
}
__device__ __forceinline__ float bf2f(unsigned short h) {
  return __builtin_bit_cast(float, (unsigned)h << 16);
}

__device__ __forceinline__ void gload_lds16(const void* g, void* l) {
  __builtin_amdgcn_global_load_lds(
      (const __attribute__((address_space(1))) void*)g,
      (__attribute__((address_space(3))) void*)l, 16, 0, 0);
}

// ---------------- fp32 -> bf16 conversion ----------------
__global__ __launch_bounds__(256) void cvt_kernel(const float* __restrict__ src,
                                                  unsigned short* __restrict__ dst, int n4) {
  int i = blockIdx.x * 256 + threadIdx.x;
  int stride = gridDim.x * 256;
  for (; i < n4; i += stride) {
    float4 v = reinterpret_cast<const float4*>(src)[i];
    us4 o = { f2bf(v.x), f2bf(v.y), f2bf(v.z), f2bf(v.w) };
    reinterpret_cast<us4*>(dst)[i] = o;
  }
}

// ---------------- 128x128-tile bf16 MFMA GEMM ----------------
// EPI 0: LDS-transpose epilogue (validated R11: <=111us vs 140us scatter)
// EPI 1: direct fp32 Cout[M,N]
template<int EPI>
__global__ __launch_bounds__(256) void gemm128(
    const unsigned short* __restrict__ A, const unsigned short* __restrict__ Bw,
    const float* __restrict__ bias,
    unsigned short* __restrict__ Qb, unsigned short* __restrict__ Kb,
    unsigned short* __restrict__ Vtb, float* __restrict__ Cout,
    int M, int N, int K)
{
  __shared__ __align__(16) unsigned short S[8704];   // As | Bs, reused as Ls[64][136]
  unsigned short* As = S;
  unsigned short* Bs = S + 4096;
  const int n0 = blockIdx.x * 128, m0 = blockIdx.y * 128;
  const int tid = threadIdx.x;
  const int w = tid >> 6, l = tid & 63, r = l & 15, g = l >> 4;
  const int wm = w >> 1, wn = w & 1;
  const int ldRow = tid >> 2, ldCol = (tid & 3) * 8;
  f32x4 acc[4][4] = {};

  const unsigned short* Ar0 = A  + (size_t)(m0 +      ldRow) * K + ldCol;
  const unsigned short* Ar1 = A  + (size_t)(m0 + 64 + ldRow) * K + ldCol;
  const unsigned short* Br0 = Bw + (size_t)(n0 +      ldRow) * K + ldCol;
  const unsigned short* Br1 = Bw + (size_t)(n0 + 64 + ldRow) * K + ldCol;
  char* Ab0 = (char*)As        + w * 1024;
  char* Ab1 = (char*)As + 4096 + w * 1024;
  char* Bb0 = (char*)Bs        + w * 1024;
  char* Bb1 = (char*)Bs + 4096 + w * 1024;

  for (int k0 = 0; k0 < K; k0 += 32) {
    __syncthreads();
    gload_lds16(Ar0 + k0, Ab0);
    gload_lds16(Ar1 + k0, Ab1);
    gload_lds16(Br0 + k0, Bb0);
    gload_lds16(Br1 + k0, Bb1);
    __syncthreads();
    bf16x8 a[4], b[4];
    #pragma unroll
    for (int i = 0; i < 4; ++i) a[i] = *(const bf16x8*)&As[(wm*64 + i*16 + r)*32 + g*8];
    #pragma unroll
    for (int j = 0; j < 4; ++j) b[j] = *(const bf16x8*)&Bs[(wn*64 + j*16 + r)*32 + g*8];
    #pragma unroll
    for (int i = 0; i < 4; ++i)
      #pragma unroll
      for (int j = 0; j < 4; ++j)
        acc[i][j] = __builtin_amdgcn_mfma_f32_16x16x32_bf16(a[i], b[j], acc[i][j], 0, 0, 0);
  }

  if (EPI == 0) {
    // LDS-transpose epilogue: stage acc into Ls[64 cols][136], store coalesced
    const int which = n0 >> 10;
    __syncthreads();
    #pragma unroll
    for (int hh = 0; hh < 2; ++hh) {
      if (hh) __syncthreads();
      if (wn == hh) {
        #pragma unroll
        for (int i = 0; i < 4; ++i)
          #pragma unroll
          for (int j = 0; j < 4; ++j) {
            int c = j*16 + r;
            float bv = bias[n0 + hh*64 + c];
            int t = wm*64 + i*16 + 4*g;
            us4 pk = { f2bf(acc[i][j][0]+bv), f2bf(acc[i][j][1]+bv),
                       f2bf(acc[i][j][2]+bv), f2bf(acc[i][j][3]+bv) };
            *(us4*)&S[c*136 + t] = pk;
          }
      }
      __syncthreads();
      const int hd = (n0 & 1023) + hh*64;
      const int h  = hd >> 6;
      if (which == 2) {
        int d = tid >> 2, tp = tid & 3;
        int bh = (m0 >> 11)*Hq + h;
        size_t base = ((size_t)(bh*Dq + d))*Tq + (m0 & 2047) + tp*32;
        const unsigned short* Lr = &S[d*136 + tp*32];
        #pragma unroll
        for (int q4 = 0; q4 < 4; ++q4)
          *(bf16x8*)&Vtb[base + q4*8] = *(const bf16x8*)&Lr[q4*8];
      } else {
        unsigned short* dst = which ? Kb : Qb;
        int t = tid >> 1, dp = tid & 1;
        int gr = m0 + t;
        int bh = (gr >> 11)*Hq + h;
        size_t base = ((size_t)(bh*Tq + (gr & 2047)))*Dq + dp*32;
        #pragma unroll
        for (int q4 = 0; q4 < 4; ++q4) {
          bf16x8 vv;
          #pragma unroll
          for (int e = 0; e < 8; ++e)
            vv[e] = (short)S[(dp*32 + q4*8 + e)*136 + t];
          *(bf16x8*)&dst[base + q4*8] = vv;
        }
      }
    }
  } else {
    #pragma unroll
    for (int i = 0; i < 4; ++i)
      #pragma unroll
      for (int j = 0; j < 4; ++j) {
        int gc = n0 + wn*64 + j*16 + r;
        float bv = bias[gc];
        #pragma unroll
        for (int jj = 0; jj < 4; ++jj) {
          int gr = m0 + wm*64 + i*16 + 4*g + jj;
          Cout[(size_t)gr * N + gc] = acc[i][j][jj] + bv;
        }
      }
  }
}

// ---------------- causal attention: zero-tails interleaved into pass A ---------------
// Block = 512 thr (8 waves), pair (p, 127-p); 65 compute chunks + 63 zero-chunks,
// both striped ci ≡ w (mod 8).  Zero-chunks (16 rows x 32 cols fp32 zeros) are
// fire-and-forget nt stores issued during pass A -> store pipe busy from t=0.
// Pass B: waves 0-3 store normalized data region [0,Lc) only; waves 4-7 PV + ctx.
#define PROWB 4224   // row stride bytes (2112 bf16) = 33*128
#define XMASK(row_) ((((row_) & 7) << 4) ^ ((((row_) >> 2) & 3) << 5))

__global__ __launch_bounds__(512, 4) void attn_kernel(
    const unsigned short* __restrict__ Qb, const unsigned short* __restrict__ Kb,
    const unsigned short* __restrict__ Vtb,
    float* __restrict__ attn, unsigned short* __restrict__ ctxb)
{
  __shared__ __align__(16) unsigned short P[16][2112];   // 66 KB
  __shared__ float red[8][32];
  __shared__ float invl_s[32];

  const int p  = blockIdx.x;
  const int bh = blockIdx.y;
  const int tid = threadIdx.x, w = tid >> 6, l = tid & 63, r = l & 15, g = l >> 4;
  const int qbA = p * 16, qbB = (127 - p) * 16;
  const int NA = (qbA + 16 + 31) >> 5;
  const int NB = (qbB + 16 + 31) >> 5;   // NA + NB == 65
  const int LAc = NA * 32, LBc = NB * 32;
  const int nzA = 64 - NA;               // zero-chunks in strip A (total 63)

  const unsigned short* Qp = Qb  + (size_t)bh * Tq * Dq;
  const unsigned short* Kp = Kb  + (size_t)bh * Tq * Dq;
  const unsigned short* Vp = Vtb + (size_t)bh * Dq * Tq;
  char* Pmut = (char*)&P[0][0];

  bf16x8 aqA0 = *(const bf16x8*)&Qp[(size_t)(qbA + r)*Dq      + g*8];
  bf16x8 aqA1 = *(const bf16x8*)&Qp[(size_t)(qbA + r)*Dq + 32 + g*8];
  bf16x8 aqB0 = *(const bf16x8*)&Qp[(size_t)(qbB + r)*Dq      + g*8];
  bf16x8 aqB1 = *(const bf16x8*)&Qp[(size_t)(qbB + r)*Dq + 32 + g*8];

  float lsumA[4] = {0.f,0.f,0.f,0.f}, lsumB[4] = {0.f,0.f,0.f,0.f};

#define LOADK(ci_, D00, D01, D10, D11)                                              \
  {                                                                                 \
    int cj_ = ((ci_) < NA) ? (ci_) : (ci_) - NA;                                    \
    int k0c_ = cj_ * 32;                                                            \
    D00 = *(const bf16x8*)&Kp[(size_t)(k0c_ + r)*Dq      + g*8];                    \
    D01 = *(const bf16x8*)&Kp[(size_t)(k0c_ + r)*Dq + 32 + g*8];                    \
    D10 = *(const bf16x8*)&Kp[(size_t)(k0c_ + 16 + r)*Dq      + g*8];               \
    D11 = *(const bf16x8*)&Kp[(size_t)(k0c_ + 16 + r)*Dq + 32 + g*8];               \
  }

  // ---- pass A (with interleaved zero-tail stores) ----
  {
    const f32x4 zero4 = {0.f,0.f,0.f,0.f};
    bf16x8 k00, k01, k10, k11, n00, n01, n10, n11;
    int ci = w;
    if (ci < 65) LOADK(ci, k00, k01, k10, k11);
    for (; ci < 65; ci += 8) {
      if (ci + 8 < 65) LOADK(ci + 8, n00, n01, n10, n11);
      // fire-and-forget zero-chunk (pairs 1:1 with compute chunks; 63 total)
      if (ci < 63) {
        int zq, zc;
        if (ci < nzA) { zq = qbA; zc = LAc + ci*32; }
        else          { zq = qbB; zc = LBc + (ci - nzA)*32; }
        size_t zb = ((size_t)bh*Tq + zq + (l >> 2))*Tq + zc + (l & 3)*8;
        __builtin_nontemporal_store(zero4, (f32x4*)&attn[zb]);
        __builtin_nontemporal_store(zero4, (f32x4*)&attn[zb + 4]);
      }
      const bool isA = ci < NA;
      const int cj  = isA ? ci : ci - NA;
      const int k0c = cj * 32;
      const int qb_ = isA ? qbA : qbB;
      const int cb_ = isA ? k0c : LAc + k0c;
      bf16x8 q0_ = isA ? aqA0 : aqB0;
      bf16x8 q1_ = isA ? aqA1 : aqB1;
      f32x4 z = {0.f,0.f,0.f,0.f};
      __builtin_amdgcn_s_setprio(1);
      f32x4 s0 = __builtin_amdgcn_mfma_f32_16x16x32_bf16(q0_, k00, z, 0, 0, 0);
      s0 = __builtin_amdgcn_mfma_f32_16x16x32_bf16(q1_, k01, s0, 0, 0, 0);
      f32x4 s1 = __builtin_amdgcn_mfma_f32_16x16x32_bf16(q0_, k10, z, 0, 0, 0);
      s1 = __builtin_amdgcn_mfma_f32_16x16x32_bf16(q1_, k11, s1, 0, 0, 0);
      __builtin_amdgcn_s_setprio(0);
      float tch[4];
      #pragma unroll
      for (int jj = 0; jj < 4; ++jj) {
        int q = qb_ + 4*g + jj;
        float p0 = (k0c + r      <= q) ? __expf(s0[jj]*0.125f) : 0.f;
        float p1 = (k0c + 16 + r <= q) ? __expf(s1[jj]*0.125f) : 0.f;
        tch[jj] = p0 + p1;
        int row = 4*g + jj, xm = XMASK(row);
        *(unsigned short*)(Pmut + row*PROWB + (((cb_ + r)*2)      ^ xm)) = f2bf(p0);
        *(unsigned short*)(Pmut + row*PROWB + (((cb_ + 16 + r)*2) ^ xm)) = f2bf(p1);
      }
      if (isA) { lsumA[0]+=tch[0]; lsumA[1]+=tch[1]; lsumA[2]+=tch[2]; lsumA[3]+=tch[3]; }
      else     { lsumB[0]+=tch[0]; lsumB[1]+=tch[1]; lsumB[2]+=tch[2]; lsumB[3]+=tch[3]; }
      k00 = n00; k01 = n01; k10 = n10; k11 = n11;
    }
  }

  // ---- row-sum reduction ----
  #pragma unroll
  for (int jj = 0; jj < 4; ++jj) {
    float sa = lsumA[jj], sb = lsumB[jj];
    #pragma unroll
    for (int off = 1; off < 16; off <<= 1) {
      sa += __shfl_xor(sa, off, 64);
      sb += __shfl_xor(sb, off, 64);
    }
    if (r == 0) { red[w][4*g + jj] = sa; red[w][16 + 4*g + jj] = sb; }
  }
  __syncthreads();
  if (tid < 32) {
    float s = 0.f;
    #pragma unroll
    for (int ww = 0; ww < 8; ++ww) s += red[ww][tid];
    invl_s[tid] = 1.f / s;
  }
  __syncthreads();

  // ---- pass B: wave-specialized, concurrent (data region only) ----
  if (w < 4) {
    #pragma unroll
    for (int s = 0; s < 2; ++s) {
      const int idx   = s * 256 + tid;
      const int s16   = idx >> 8;            // 0 = strip A, 1 = strip B
      const int row16 = (idx >> 4) & 15;
      const int seg   = (idx & 15) * 8;
      const int xm16  = XMASK(row16);
      const char* Prow = Pmut + row16 * PROWB;
      const int Lc    = s16 ? LBc : LAc;
      const int cbase = s16 ? LAc : 0;
      float inv = invl_s[s16*16 + row16];
      size_t ob = ((size_t)bh*Tq + (s16 ? qbB : qbA) + row16) * Tq;
      for (int cb = seg; cb < Lc; cb += 128) {
        bf16x8 pv = *(const bf16x8*)(Prow + (((cbase + cb)*2) ^ xm16));
        f32x4 v0, v1;
        v0[0]=bf2f((unsigned short)pv[0])*inv; v0[1]=bf2f((unsigned short)pv[1])*inv;
        v0[2]=bf2f((unsigned short)pv[2])*inv; v0[3]=bf2f((unsigned short)pv[3])*inv;
        v1[0]=bf2f((unsigned short)pv[4])*inv; v1[1]=bf2f((unsigned short)pv[5])*inv;
        v1[2]=bf2f((unsigned short)pv[6])*inv; v1[3]=bf2f((unsigned short)pv[7])*inv;
        __builtin_nontemporal_store(v0, (f32x4*)&attn[ob + cb]);
        __builtin_nontemporal_store(v1, (f32x4*)&attn[ob + cb + 4]);
      }
    }
  } else {
    const int dblk = w - 4;
    const char* Pr = Pmut + r * PROWB;
    const int xr = XMASK(r);
    const unsigned short* Vrow = &Vp[(size_t)(dblk*16 + r) * Tq];
    f32x4 coA0 = {0.f,0.f,0.f,0.f}, coA1 = {0.f,0.f,0.f,0.f};
    f32x4 coB0 = {0.f,0.f,0.f,0.f}, coB1 = {0.f,0.f,0.f,0.f};
    bf16x8 pa, bv, pan, bvn;
    {
      pa = *(const bf16x8*)(Pr + (((0 + g*8)*2) ^ xr));
      bv = *(const bf16x8*)&Vrow[g*8];
    }
    for (int ci = 0; ci < 65; ++ci) {
      if (ci + 1 < 65) {
        int cn = ci + 1;
        int cj = (cn < NA) ? cn : cn - NA;
        int cb = (cn < NA) ? cn*32 : LAc + cj*32;
        pan = *(const bf16x8*)(Pr + (((cb + g*8)*2) ^ xr));
        bvn = *(const bf16x8*)&Vrow[cj*32 + g*8];
      }
      if (ci < NA) {
        if (ci & 1) coA1 = __builtin_amdgcn_mfma_f32_16x16x32_bf16(pa, bv, coA1, 0, 0, 0);
        else        coA0 = __builtin_amdgcn_mfma_f32_16x16x32_bf16(pa, bv, coA0, 0, 0, 0);
      } else {
        if (ci & 1) coB1 = __builtin_amdgcn_mfma_f32_16x16x32_bf16(pa, bv, coB1, 0, 0, 0);
        else        coB0 = __builtin_amdgcn_mfma_f32_16x16x32_bf16(pa, bv, coB0, 0, 0, 0);
      }
      pa = pan; bv = bvn;
    }
    const int b = bh >> 4, h = bh & 15;
    #pragma unroll
    for (int jj = 0; jj < 4; ++jj) {
      int tA = qbA + 4*g + jj;
      ctxb[(size_t)(b*Tq + tA)*Cq + h*Dq + dblk*16 + r] =
          f2bf((coA0[jj] + coA1[jj]) * invl_s[4*g + jj]);
      int tB = qbB + 4*g + jj;
      ctxb[(size_t)(b*Tq + tB)*Cq + h*Dq + dblk*16 + r] =
          f2bf((coB0[jj] + coB1[jj]) * invl_s[16 + 4*g + jj]);
    }
  }
#undef LOADK
}

// ---------------- launch ----------------
extern "C" void kernel_launch(void* const* d_in, const int* in_sizes, int n_in,
                              void* d_out, int out_size, void* d_ws, size_t ws_size,
                              hipStream_t stream) {
  const float* x     = (const float*)d_in[0];
  const float* qkv_w = (const float*)d_in[1];
  const float* qkv_b = (const float*)d_in[2];
  const float* out_w = (const float*)d_in[3];
  const float* out_b = (const float*)d_in[4];
  float* out  = (float*)d_out;
  float* attn = out + (size_t)BTq * Cq;   // second output: [B,H,T,T]

  char* ws = (char*)d_ws;
  unsigned short* xb    = (unsigned short*)(ws);
  unsigned short* wqkvb = (unsigned short*)(ws + (16u << 20));
  unsigned short* woutb = (unsigned short*)(ws + (22u << 20));
  unsigned short* Qb    = (unsigned short*)(ws + (24u << 20));
  unsigned short* Kb    = (unsigned short*)(ws + (40u << 20));
  unsigned short* Vtb   = (unsigned short*)(ws + (56u << 20));
  unsigned short* ctxb  = (unsigned short*)(ws + (72u << 20));

  cvt_kernel<<<2048, 256, 0, stream>>>(x,     xb,    (BTq * Cq) / 4);
  cvt_kernel<<<1024, 256, 0, stream>>>(qkv_w, wqkvb, (C3q * Cq) / 4);
  cvt_kernel<<<512,  256, 0, stream>>>(out_w, woutb, (Cq * Cq) / 4);

  dim3 g1(C3q / 128, BTq / 128);   // 24 x 64
  gemm128<0><<<g1, 256, 0, stream>>>(xb, wqkvb, qkv_b, Qb, Kb, Vtb, nullptr, BTq, C3q, Cq);

  dim3 g2(64, Bq * Hq);            // strip-pairs x bh
  attn_kernel<<<g2, 512, 0, stream>>>(Qb, Kb, Vtb, attn, ctxb);

  dim3 g3(Cq / 128, BTq / 128);    // 8 x 64
  gemm128<1><<<g3, 256, 0, stream>>>(ctxb, woutb, out_b, nullptr, nullptr, nullptr, out, BTq, Cq, Cq);
}